// Round 3
// baseline (3626.358 us; speedup 1.0000x reference)
//
#include <hip/hip_runtime.h>
#include <hip/hip_bf16.h>

typedef float f32x4 __attribute__((ext_vector_type(4)));
typedef short s16x8 __attribute__((ext_vector_type(8)));
typedef int   i32x4 __attribute__((ext_vector_type(4)));
typedef _Float16 h16x8 __attribute__((ext_vector_type(8)));

#define NV 1024
#define ND 1024
#define NJ 1024
#define NB 64
#define NU 512
#define NT 513            // U+1 steps
#define G3 3072           // 3*D
#define SLOT 65536        // NB*ND elements per h slot
#define NWG 64            // recurrence workgroups
#define NOUT 192          // fused output-GEMM workgroups
#define NTILE 8208        // 513 * 16 output tiles
#define FSTRIDE 32        // flags spread: one per 128-B line
#define CANARY 0x7FFF7FFFu   // fp16 all-ones NaN pair: unreachable by f2h(h)

static __device__ __forceinline__ unsigned short f2h(float f) {
  union { _Float16 h; unsigned short u; } x; x.h = (_Float16)f;   // RNE
  return x.u;
}

// Swizzled fp16 layout (K=1024 -> 32 k-chunks of 32):
// element (r,k) -> flat ((r>>4)*32 + (k>>5))*512 + ((r&15) | (((k>>3)&3)<<4))*8 + (k&7)
// = exact mfma_f32_16x16x32_f16 A/B fragment order (64 lanes x 16B contiguous).
static __device__ __forceinline__ void unswizzle(long e, int& r, int& k) {
  long blk = e >> 9; int l = (int)((e >> 3) & 63); int j = (int)(e & 7);
  r = (int)(blk >> 5) * 16 + (l & 15);
  k = ((int)(blk & 31)) * 32 + ((l >> 4) << 3) + j;
}

__global__ void predictor_prep(const float* __restrict__ whh, const float* __restrict__ wih,
                               const float* __restrict__ em, const float* __restrict__ lw,
                               const float* __restrict__ bih, const float* __restrict__ bhh,
                               const float* __restrict__ init,
                               unsigned short* __restrict__ wh_sw, unsigned short* __restrict__ wi_sw,
                               unsigned short* __restrict__ em_sw, unsigned short* __restrict__ lw_sw,
                               float* __restrict__ bias_sum, unsigned short* __restrict__ hs,
                               unsigned int* __restrict__ flags) {
  long e = (long)blockIdx.x * 256 + threadIdx.x;
  const long nbig = 3145728, nsm = 1048576;
  if (e < nbig) { int r, k; unswizzle(e, r, k); wh_sw[e] = f2h(whh[(long)r * 1024 + k]); return; }
  e -= nbig;
  if (e < nbig) { int r, k; unswizzle(e, r, k); wi_sw[e] = f2h(wih[(long)r * 1024 + k]); return; }
  e -= nbig;
  if (e < nsm) { int r, k; unswizzle(e, r, k); em_sw[e] = f2h(em[(long)r * 1024 + k]); return; }
  e -= nsm;
  if (e < nsm) { int r, k; unswizzle(e, r, k); lw_sw[e] = f2h(lw[(long)r * 1024 + k]); return; }
  e -= nsm;
  if (e < 65536) { int r, k; unswizzle(e, r, k); hs[e] = f2h(init[k]); return; }
  e -= 65536;
  if (e < 3072) { bias_sum[e] = bih[e] + bhh[e]; return; }
  e -= 3072;
  if (e < 8192) { flags[e] = 0u; return; }     // 256 flags * 32-dword spread
  e -= 8192;
  if (e < 4202752) {  // canary-fill slots 1..513 (513*65536 ushort / 8 per thread)
    s16x8 c = { (short)0x7FFF, (short)0x7FFF, (short)0x7FFF, (short)0x7FFF,
                (short)0x7FFF, (short)0x7FFF, (short)0x7FFF, (short)0x7FFF };
    *(s16x8*)(hs + 65536 + e * 8) = c;
  }
}

// Generic fp16 GEMM (used for the gtab build): out[row, nt*64..+64) = A@B^T + bias.
__global__ __launch_bounds__(256) void predictor_gemm(
    const unsigned short* __restrict__ A, long a_chunk_stride,
    const unsigned short* __restrict__ Bw,
    const float* __restrict__ bias, float* __restrict__ out,
    int rowmul_i, int rowmul_c, int out_stride) {
  const int nt = blockIdx.x, chunk = blockIdx.y;
  const int tid = threadIdx.x, lane = tid & 63, wave = tid >> 6;
  const unsigned short* Ab = A + (long)chunk * a_chunk_stride + wave * 16384 + lane * 8;
  const unsigned short* Bb = Bw + (long)nt * 65536 + lane * 8;
  f32x4 a0 = {0,0,0,0}, a1 = {0,0,0,0}, a2 = {0,0,0,0}, a3 = {0,0,0,0};
#pragma unroll 4
  for (int kc = 0; kc < 32; ++kc) {
    h16x8 av = __builtin_bit_cast(h16x8, *(const s16x8*)(Ab + kc * 512));
    h16x8 w0 = __builtin_bit_cast(h16x8, *(const s16x8*)(Bb + kc * 512));
    h16x8 w1 = __builtin_bit_cast(h16x8, *(const s16x8*)(Bb + 16384 + kc * 512));
    h16x8 w2 = __builtin_bit_cast(h16x8, *(const s16x8*)(Bb + 32768 + kc * 512));
    h16x8 w3 = __builtin_bit_cast(h16x8, *(const s16x8*)(Bb + 49152 + kc * 512));
    a0 = __builtin_amdgcn_mfma_f32_16x16x32_f16(av, w0, a0, 0, 0, 0);
    a1 = __builtin_amdgcn_mfma_f32_16x16x32_f16(av, w1, a1, 0, 0, 0);
    a2 = __builtin_amdgcn_mfma_f32_16x16x32_f16(av, w2, a2, 0, 0, 0);
    a3 = __builtin_amdgcn_mfma_f32_16x16x32_f16(av, w3, a3, 0, 0, 0);
  }
  const int q = lane >> 4, nl = lane & 15, colbase = nt << 6;
#pragma unroll
  for (int j = 0; j < 4; ++j) {
    int il = (wave << 4) + (q << 2) + j;
    long row = (long)il * rowmul_i + (long)chunk * rowmul_c;
    float* orow = out + row * out_stride + colbase;
    orow[nl]      = a0[j] + bias[colbase + nl];
    orow[16 + nl] = a1[j] + bias[colbase + 16 + nl];
    orow[32 + nl] = a2[j] + bias[colbase + 32 + nl];
    orow[48 + nl] = a3[j] + bias[colbase + 48 + nl];
  }
}

#define PINSTAGE(CNT, B)                                                        \
  asm volatile("s_waitcnt vmcnt(" #CNT ")"                                      \
    : "+v"(hf[(B)*8+0]), "+v"(hf[(B)*8+1]), "+v"(hf[(B)*8+2]), "+v"(hf[(B)*8+3]), \
      "+v"(hf[(B)*8+4]), "+v"(hf[(B)*8+5]), "+v"(hf[(B)*8+6]), "+v"(hf[(B)*8+7]) :: "memory")

// Canary-validate group B (safety net for the drain-free flag publish).
// Flag poll precedes the loads, so the first check passes ~always; the retry
// path only fires if the producer's flag beat its data through the fabric.
#define PVALID(B, CNT)                                                          \
  {                                                                             \
    PINSTAGE(CNT, B);                                                           \
    for (;;) {                                                                  \
      int ok = 1;                                                               \
      _Pragma("unroll")                                                         \
      for (int i = 0; i < 8; ++i) {                                             \
        i32x4 v = hf[(B)*8 + i];                                                \
        ok &= (v[0] != (int)CANARY) & (v[1] != (int)CANARY) &                   \
              (v[2] != (int)CANARY) & (v[3] != (int)CANARY);                    \
      }                                                                         \
      if (__all(ok)) break;                                                     \
      __builtin_amdgcn_s_sleep(1);                                              \
      _Pragma("unroll")                                                         \
      for (int i = 0; i < 8; ++i) {                                             \
        const unsigned short* a2_ = hprev + (B)*16384 + ((w<<3)+i)*512 + lane*8;\
        asm volatile("global_load_dwordx4 %0, %1, off sc1"                      \
                     : "=v"(hf[(B)*8+i]) : "v"(a2_) : "memory");                \
      }                                                                         \
      PINSTAGE(0, B);                                                           \
    }                                                                           \
  }

// Fused persistent kernel:
//  blockIdx < 64 : recurrence role (R1 structure + drain-free publish + canary net)
//  blockIdx >= 64: output-GEMM role (192 WGs) — consumes h slots as flags appear,
//                  computing out[b, t, :] tiles overlapped under the recurrence.
__global__ __launch_bounds__(256, 1) void predictor_fused(
    const unsigned short* __restrict__ wh_sw, const float* __restrict__ gtab,
    const int* __restrict__ y, const float* __restrict__ init,
    unsigned short* __restrict__ hs, unsigned int* __restrict__ flags,
    const unsigned short* __restrict__ lw_sw, const float* __restrict__ lb,
    float* __restrict__ out) {
  __shared__ float buf[4][3][4][64][4];   // K-reduction exchange, 48 KB (rnn role)
  __shared__ unsigned short tbuf[1024];   // h store transpose, 2 KB (rnn role)
  const int wg = blockIdx.x, tid = threadIdx.x, lane = tid & 63, w = tid >> 6;

  if (wg < NWG) {
    // ================= recurrence role =================
    const int q = lane >> 4, dloc = lane & 15, dg = (wg << 4) + dloc;

    h16x8 wrf[8], wzf[8], wnf[8];
#pragma unroll
    for (int i = 0; i < 8; ++i) {
      int kc = (w << 3) + i;
      wrf[i] = __builtin_bit_cast(h16x8, *(const s16x8*)(wh_sw + ((long)(      wg) << 14) + kc * 512 + lane * 8));
      wzf[i] = __builtin_bit_cast(h16x8, *(const s16x8*)(wh_sw + ((long)( 64 + wg) << 14) + kc * 512 + lane * 8));
      wnf[i] = __builtin_bit_cast(h16x8, *(const s16x8*)(wh_sw + ((long)(128 + wg) << 14) + kc * 512 + lane * 8));
    }
    float hreg[4];
#pragma unroll
    for (int j = 0; j < 4; ++j) hreg[j] = init[dg];

    for (int t = 1; t <= NT; ++t) {
      // ---- issue gate-table prefetch (drained for free by the poll) ----
      float gr[4], gz[4], gn[4];
#pragma unroll
      for (int j = 0; j < 4; ++j) {
        int b = (w << 4) + (q << 2) + j;
        int tok = (t == 1) ? 0 : y[b * NU + (t - 2)];
        const float* g = gtab + (long)tok * G3 + dg;
        asm volatile("global_load_dword %0, %1, off" : "=v"(gr[j]) : "v"(g) : "memory");
        asm volatile("global_load_dword %0, %1, off" : "=v"(gz[j]) : "v"(g + 1024) : "memory");
        asm volatile("global_load_dword %0, %1, off" : "=v"(gn[j]) : "v"(g + 2048) : "memory");
      }

      // ---- per-wave poll: this wave's 64 producer flags ----
      if (t > 1) {
        const unsigned int* fp = flags + (unsigned)((w << 6) + lane) * FSTRIDE;
        const unsigned int tm1 = (unsigned)(t - 1);
        for (;;) {
          unsigned int v;
          asm volatile("global_load_dword %0, %1, off sc1" : "=v"(v) : "v"(fp) : "memory");
          asm volatile("s_waitcnt vmcnt(0)" : "+v"(v) :: "memory");
          if (__all((int)(v >= tm1))) break;
          __builtin_amdgcn_s_sleep(1);
        }
      }
      // tie gtab registers (vmcnt already 0 after the poll)
      asm volatile("s_waitcnt vmcnt(0)"
        : "+v"(gr[0]), "+v"(gr[1]), "+v"(gr[2]), "+v"(gr[3]),
          "+v"(gz[0]), "+v"(gz[1]), "+v"(gz[2]), "+v"(gz[3]),
          "+v"(gn[0]), "+v"(gn[1]), "+v"(gn[2]), "+v"(gn[3]) :: "memory");

      const unsigned short* hprev = hs + (long)(t - 1) * SLOT;
      unsigned short* hcur = hs + (long)t * SLOT;

      // ---- 32 h-fragment loads; staged consume + canary validation ----
      i32x4 hf[32];
#pragma unroll
      for (int bg = 0; bg < 4; ++bg)
#pragma unroll
        for (int i = 0; i < 8; ++i) {
          const unsigned short* a = hprev + bg * 16384 + ((w << 3) + i) * 512 + lane * 8;
          asm volatile("global_load_dwordx4 %0, %1, off sc1" : "=v"(hf[bg * 8 + i]) : "v"(a) : "memory");
        }
      f32x4 aR[4], aZ[4], aN[4];
#pragma unroll
      for (int bg = 0; bg < 4; ++bg) { aR[bg] = (f32x4){0,0,0,0}; aZ[bg] = (f32x4){0,0,0,0}; aN[bg] = (f32x4){0,0,0,0}; }

      PVALID(0, 24);
#pragma unroll
      for (int i = 0; i < 8; ++i) { h16x8 a = __builtin_bit_cast(h16x8, hf[0 * 8 + i]);
        aR[0] = __builtin_amdgcn_mfma_f32_16x16x32_f16(a, wrf[i], aR[0], 0, 0, 0);
        aZ[0] = __builtin_amdgcn_mfma_f32_16x16x32_f16(a, wzf[i], aZ[0], 0, 0, 0);
        aN[0] = __builtin_amdgcn_mfma_f32_16x16x32_f16(a, wnf[i], aN[0], 0, 0, 0); }
      PVALID(1, 16);
#pragma unroll
      for (int i = 0; i < 8; ++i) { h16x8 a = __builtin_bit_cast(h16x8, hf[1 * 8 + i]);
        aR[1] = __builtin_amdgcn_mfma_f32_16x16x32_f16(a, wrf[i], aR[1], 0, 0, 0);
        aZ[1] = __builtin_amdgcn_mfma_f32_16x16x32_f16(a, wzf[i], aZ[1], 0, 0, 0);
        aN[1] = __builtin_amdgcn_mfma_f32_16x16x32_f16(a, wnf[i], aN[1], 0, 0, 0); }
      PVALID(2, 8);
#pragma unroll
      for (int i = 0; i < 8; ++i) { h16x8 a = __builtin_bit_cast(h16x8, hf[2 * 8 + i]);
        aR[2] = __builtin_amdgcn_mfma_f32_16x16x32_f16(a, wrf[i], aR[2], 0, 0, 0);
        aZ[2] = __builtin_amdgcn_mfma_f32_16x16x32_f16(a, wzf[i], aZ[2], 0, 0, 0);
        aN[2] = __builtin_amdgcn_mfma_f32_16x16x32_f16(a, wnf[i], aN[2], 0, 0, 0); }
      PVALID(3, 0);
#pragma unroll
      for (int i = 0; i < 8; ++i) { h16x8 a = __builtin_bit_cast(h16x8, hf[3 * 8 + i]);
        aR[3] = __builtin_amdgcn_mfma_f32_16x16x32_f16(a, wrf[i], aR[3], 0, 0, 0);
        aZ[3] = __builtin_amdgcn_mfma_f32_16x16x32_f16(a, wzf[i], aZ[3], 0, 0, 0);
        aN[3] = __builtin_amdgcn_mfma_f32_16x16x32_f16(a, wnf[i], aN[3], 0, 0, 0); }

      // ---- cross-wave K-reduction via LDS ----
#pragma unroll
      for (int b2 = 0; b2 < 4; ++b2)
        if (b2 != w) {
          *(f32x4*)&buf[w][0][b2][lane][0] = aR[b2];
          *(f32x4*)&buf[w][1][b2][lane][0] = aZ[b2];
          *(f32x4*)&buf[w][2][b2][lane][0] = aN[b2];
        }
      __syncthreads();
      f32x4 sR = aR[w], sZ = aZ[w], sN = aN[w];
#pragma unroll
      for (int v = 0; v < 4; ++v)
        if (v != w) {
          sR += *(const f32x4*)&buf[v][0][w][lane][0];
          sZ += *(const f32x4*)&buf[v][1][w][lane][0];
          sN += *(const f32x4*)&buf[v][2][w][lane][0];
        }
      __syncthreads();   // buf WAR protection vs next iteration's writes

      // ---- gate epilogue; fp32 h chain in registers; fp16 h to wave-private tbuf ----
#pragma unroll
      for (int j = 0; j < 4; ++j) {
        float r = 1.f / (1.f + __expf(-(gr[j] + sR[j])));
        float z = 1.f / (1.f + __expf(-(gz[j] + sZ[j])));
        float np = gn[j] + r * sN[j];
        float e2 = __expf(-2.f * fabsf(np));              // overflow-safe tanh
        float tn = (1.f - e2) / (1.f + e2);
        tn = np < 0.f ? -tn : tn;
        float hnew = (1.f - z) * tn + z * hreg[j];
        hreg[j] = hnew;
        tbuf[(w << 8) + ((((q << 2) + j) | ((dloc >> 3) << 4)) << 3) + (dloc & 7)] = f2h(hnew);
      }
      asm volatile("s_waitcnt lgkmcnt(0)" ::: "memory");  // wave-private transpose done

      // ---- drain-free publish: data store then flag, no vmcnt between ----
      {
        unsigned long long pv = *(const unsigned long long*)(tbuf + (w << 8) + lane * 4);
        unsigned short* gp = hcur + ((long)(w * 32 + (wg >> 1)) << 9) + ((wg & 1) << 8) + lane * 4;
        asm volatile("global_store_dwordx2 %0, %1, off sc1" :: "v"(gp), "v"(pv) : "memory");
        if (lane == 0)
          __hip_atomic_store(&flags[((wg << 2) + w) * FSTRIDE], (unsigned)t,
                             __ATOMIC_RELAXED, __HIP_MEMORY_SCOPE_AGENT);
        // no drain: consumers canary-validate; our next poll's vmcnt(0) retires these.
      }
    }
    return;
  }

  // ================= output-GEMM role =================
  // Tile k = t*16 + nt; needs h slot st = t+1, i.e. all 256 flags >= st.
  const int g = wg - NWG;
  for (int k = g; k < NTILE; k += NOUT) {
    const int t = k >> 4, nt = k & 15;
    const unsigned st = (unsigned)(t + 1);

    if (w == 0) {
      const unsigned int* fp = flags + lane * 4 * FSTRIDE;
      for (;;) {
        unsigned v0, v1, v2, v3;
        asm volatile("global_load_dword %0, %1, off sc1" : "=v"(v0) : "v"(fp + 0 * FSTRIDE) : "memory");
        asm volatile("global_load_dword %0, %1, off sc1" : "=v"(v1) : "v"(fp + 1 * FSTRIDE) : "memory");
        asm volatile("global_load_dword %0, %1, off sc1" : "=v"(v2) : "v"(fp + 2 * FSTRIDE) : "memory");
        asm volatile("global_load_dword %0, %1, off sc1" : "=v"(v3) : "v"(fp + 3 * FSTRIDE) : "memory");
        asm volatile("s_waitcnt vmcnt(0)" : "+v"(v0), "+v"(v1), "+v"(v2), "+v"(v3) :: "memory");
        if (__all((int)((v0 >= st) & (v1 >= st) & (v2 >= st) & (v3 >= st)))) break;
        __builtin_amdgcn_s_sleep(64);   // coarse: out-role latency has huge slack
      }
    }
    __syncthreads();

    // load + canary-validate this wave's 32 A fragments (coherent h slot reads)
    const unsigned short* Ab = hs + (long)st * SLOT + w * 16384 + lane * 8;
    i32x4 hf[32];
    for (;;) {
#pragma unroll
      for (int kc = 0; kc < 32; ++kc)
        asm volatile("global_load_dwordx4 %0, %1, off sc1" : "=v"(hf[kc]) : "v"(Ab + kc * 512) : "memory");
      PINSTAGE(0, 0); PINSTAGE(0, 1); PINSTAGE(0, 2); PINSTAGE(0, 3);
      int ok = 1;
#pragma unroll
      for (int kc = 0; kc < 32; ++kc) {
        i32x4 v = hf[kc];
        ok &= (v[0] != (int)CANARY) & (v[1] != (int)CANARY) &
              (v[2] != (int)CANARY) & (v[3] != (int)CANARY);
      }
      if (__all(ok)) break;
      __builtin_amdgcn_s_sleep(8);
    }

    const unsigned short* Bb = lw_sw + (long)nt * 65536 + lane * 8;
    f32x4 a0 = {0,0,0,0}, a1 = {0,0,0,0}, a2 = {0,0,0,0}, a3 = {0,0,0,0};
#pragma unroll 4
    for (int kc = 0; kc < 32; ++kc) {
      h16x8 av = __builtin_bit_cast(h16x8, hf[kc]);
      h16x8 w0 = __builtin_bit_cast(h16x8, *(const s16x8*)(Bb + kc * 512));
      h16x8 w1 = __builtin_bit_cast(h16x8, *(const s16x8*)(Bb + 16384 + kc * 512));
      h16x8 w2 = __builtin_bit_cast(h16x8, *(const s16x8*)(Bb + 32768 + kc * 512));
      h16x8 w3 = __builtin_bit_cast(h16x8, *(const s16x8*)(Bb + 49152 + kc * 512));
      a0 = __builtin_amdgcn_mfma_f32_16x16x32_f16(av, w0, a0, 0, 0, 0);
      a1 = __builtin_amdgcn_mfma_f32_16x16x32_f16(av, w1, a1, 0, 0, 0);
      a2 = __builtin_amdgcn_mfma_f32_16x16x32_f16(av, w2, a2, 0, 0, 0);
      a3 = __builtin_amdgcn_mfma_f32_16x16x32_f16(av, w3, a3, 0, 0, 0);
    }
    const int qq = lane >> 4, nl = lane & 15, colbase = nt << 6;
#pragma unroll
    for (int j = 0; j < 4; ++j) {
      int il = (w << 4) + (qq << 2) + j;
      long row = (long)il * 513 + t;
      float* orow = out + row * 1024 + colbase;
      orow[nl]      = a0[j] + lb[colbase + nl];
      orow[16 + nl] = a1[j] + lb[colbase + 16 + nl];
      orow[32 + nl] = a2[j] + lb[colbase + 32 + nl];
      orow[48 + nl] = a3[j] + lb[colbase + 48 + nl];
    }
  }
}

extern "C" void kernel_launch(void* const* d_in, const int* in_sizes, int n_in,
                              void* d_out, int out_size, void* d_ws, size_t ws_size,
                              hipStream_t stream) {
  const int*   y    = (const int*)d_in[0];
  const float* em   = (const float*)d_in[1];
  const float* wih  = (const float*)d_in[2];
  const float* bih  = (const float*)d_in[3];
  const float* whh  = (const float*)d_in[4];
  const float* bhh  = (const float*)d_in[5];
  const float* lw   = (const float*)d_in[6];
  const float* lb   = (const float*)d_in[7];
  const float* init = (const float*)d_in[8];
  float* out = (float*)d_out;

  char* ws = (char*)d_ws;
  size_t off = 0;
  auto alloc = [&](size_t n) { void* p = ws + off; off += (n + 255) & ~(size_t)255; return p; };
  unsigned short* wh_sw   = (unsigned short*)alloc(6291456);    // W_hh fp16 swizzled
  unsigned short* wi_sw   = (unsigned short*)alloc(6291456);    // W_ih fp16 swizzled
  unsigned short* em_sw   = (unsigned short*)alloc(2097152);    // embed fp16 swizzled
  unsigned short* lw_sw   = (unsigned short*)alloc(2097152);    // linear_w fp16 swizzled
  float*          gtab    = (float*)alloc(12582912);            // [V,3072] token gate table
  float*          bias_sum= (float*)alloc(12288);               // bias_ih + bias_hh
  unsigned int*   flags   = (unsigned int*)alloc(32768);        // 256 flags, 128-B spread
  unsigned short* hs      = (unsigned short*)alloc(67371008UL); // 514 h slots, fp16 swizzled
  (void)ws_size; (void)in_sizes; (void)n_in; (void)out_size;

  predictor_prep<<<dim3(49485), dim3(256), 0, stream>>>(
      whh, wih, em, lw, bih, bhh, init, wh_sw, wi_sw, em_sw, lw_sw, bias_sum, hs, flags);
  predictor_gemm<<<dim3(48, 16), dim3(256), 0, stream>>>(
      em_sw, 65536L, wi_sw, bias_sum, gtab, /*rowmul_i=*/1, /*rowmul_c=*/64, /*stride=*/3072);
  predictor_fused<<<dim3(NWG + NOUT), dim3(256), 0, stream>>>(
      wh_sw, gtab, y, init, hs, flags, lw_sw, lb, out);
}

// Round 4
// 3142.944 us; speedup vs baseline: 1.1538x; 1.1538x over previous
//
#include <hip/hip_runtime.h>
#include <hip/hip_bf16.h>

typedef float f32x4 __attribute__((ext_vector_type(4)));
typedef short s16x8 __attribute__((ext_vector_type(8)));
typedef int   i32x4 __attribute__((ext_vector_type(4)));
typedef _Float16 h16x8 __attribute__((ext_vector_type(8)));

#define NV 1024
#define ND 1024
#define NJ 1024
#define NB 64
#define NU 512
#define NT 513            // U+1 steps
#define G3 3072           // 3*D
#define SLOT 65536        // NB*ND elements per h slot
#define NWG 64            // recurrence workgroups

static __device__ __forceinline__ unsigned short f2h(float f) {
  union { _Float16 h; unsigned short u; } x; x.h = (_Float16)f;   // RNE
  return x.u;
}

// Swizzled fp16 layout (K=1024 -> 32 k-chunks of 32):
// element (r,k) -> flat ((r>>4)*32 + (k>>5))*512 + ((r&15) | (((k>>3)&3)<<4))*8 + (k&7)
// = exact mfma_f32_16x16x32_f16 A/B fragment order (64 lanes x 16B contiguous).
static __device__ __forceinline__ void unswizzle(long e, int& r, int& k) {
  long blk = e >> 9; int l = (int)((e >> 3) & 63); int j = (int)(e & 7);
  r = (int)(blk >> 5) * 16 + (l & 15);
  k = ((int)(blk & 31)) * 32 + ((l >> 4) << 3) + j;
}

__global__ void predictor_prep(const float* __restrict__ whh, const float* __restrict__ wih,
                               const float* __restrict__ em, const float* __restrict__ lw,
                               const float* __restrict__ bih, const float* __restrict__ bhh,
                               const float* __restrict__ init,
                               unsigned short* __restrict__ wh_sw, unsigned short* __restrict__ wi_sw,
                               unsigned short* __restrict__ em_sw, unsigned short* __restrict__ lw_sw,
                               float* __restrict__ bias_sum, unsigned short* __restrict__ hs,
                               unsigned int* __restrict__ flags) {
  long e = (long)blockIdx.x * 256 + threadIdx.x;
  const long nbig = 3145728, nsm = 1048576;
  if (e < nbig) { int r, k; unswizzle(e, r, k); wh_sw[e] = f2h(whh[(long)r * 1024 + k]); return; }
  e -= nbig;
  if (e < nbig) { int r, k; unswizzle(e, r, k); wi_sw[e] = f2h(wih[(long)r * 1024 + k]); return; }
  e -= nbig;
  if (e < nsm) { int r, k; unswizzle(e, r, k); em_sw[e] = f2h(em[(long)r * 1024 + k]); return; }
  e -= nsm;
  if (e < nsm) { int r, k; unswizzle(e, r, k); lw_sw[e] = f2h(lw[(long)r * 1024 + k]); return; }
  e -= nsm;
  if (e < 65536) { int r, k; unswizzle(e, r, k); hs[e] = f2h(init[k]); return; }
  e -= 65536;
  if (e < 3072) { bias_sum[e] = bih[e] + bhh[e]; return; }
  e -= 3072;
  if (e < 128) flags[e] = 0u;   // 4 packed flag lines (512 B)
}

// Generic fp16 GEMM: out[row, nt*64 .. +64) = A_chunk @ B^T + bias (fragment layouts).
__global__ __launch_bounds__(256) void predictor_gemm(
    const unsigned short* __restrict__ A, long a_chunk_stride,
    const unsigned short* __restrict__ Bw,
    const float* __restrict__ bias, float* __restrict__ out,
    int rowmul_i, int rowmul_c, int out_stride) {
  const int nt = blockIdx.x, chunk = blockIdx.y;
  const int tid = threadIdx.x, lane = tid & 63, wave = tid >> 6;
  const unsigned short* Ab = A + (long)chunk * a_chunk_stride + wave * 16384 + lane * 8;
  const unsigned short* Bb = Bw + (long)nt * 65536 + lane * 8;
  f32x4 a0 = {0,0,0,0}, a1 = {0,0,0,0}, a2 = {0,0,0,0}, a3 = {0,0,0,0};
#pragma unroll 4
  for (int kc = 0; kc < 32; ++kc) {
    h16x8 av = __builtin_bit_cast(h16x8, *(const s16x8*)(Ab + kc * 512));
    h16x8 w0 = __builtin_bit_cast(h16x8, *(const s16x8*)(Bb + kc * 512));
    h16x8 w1 = __builtin_bit_cast(h16x8, *(const s16x8*)(Bb + 16384 + kc * 512));
    h16x8 w2 = __builtin_bit_cast(h16x8, *(const s16x8*)(Bb + 32768 + kc * 512));
    h16x8 w3 = __builtin_bit_cast(h16x8, *(const s16x8*)(Bb + 49152 + kc * 512));
    a0 = __builtin_amdgcn_mfma_f32_16x16x32_f16(av, w0, a0, 0, 0, 0);
    a1 = __builtin_amdgcn_mfma_f32_16x16x32_f16(av, w1, a1, 0, 0, 0);
    a2 = __builtin_amdgcn_mfma_f32_16x16x32_f16(av, w2, a2, 0, 0, 0);
    a3 = __builtin_amdgcn_mfma_f32_16x16x32_f16(av, w3, a3, 0, 0, 0);
  }
  const int q = lane >> 4, nl = lane & 15, colbase = nt << 6;
#pragma unroll
  for (int j = 0; j < 4; ++j) {
    int il = (wave << 4) + (q << 2) + j;
    long row = (long)il * rowmul_i + (long)chunk * rowmul_c;
    float* orow = out + row * out_stride + colbase;
    orow[nl]      = a0[j] + bias[colbase + nl];
    orow[16 + nl] = a1[j] + bias[colbase + 16 + nl];
    orow[32 + nl] = a2[j] + bias[colbase + 32 + nl];
    orow[48 + nl] = a3[j] + bias[colbase + 48 + nl];
  }
}

#define PINSTAGE(CNT, B)                                                        \
  asm volatile("s_waitcnt vmcnt(" #CNT ")"                                      \
    : "+v"(hf[(B)*8+0]), "+v"(hf[(B)*8+1]), "+v"(hf[(B)*8+2]), "+v"(hf[(B)*8+3]), \
      "+v"(hf[(B)*8+4]), "+v"(hf[(B)*8+5]), "+v"(hf[(B)*8+6]), "+v"(hf[(B)*8+7]) :: "memory")

// Persistent recurrence v6 (= R1 structure + COALESCED FLAG LINES):
//  - flags are packed ushort step counters: line w (128 B) holds flags of
//    producer (wg, wave v) for wg in [16w,+16), v in 0..3 at offset
//    ((wg&15)*4+v)*2. Consumer wave w polls line w with ONE coalesced
//    ushort load per lane (64 lanes -> one L3 line request), vs 64 distinct
//    lines/round before. Poll fabric traffic drops ~64x; hot set = 512 B.
//  - producer: LDS transpose (wave-private, lgkmcnt) -> 512-B coalesced sc1
//    store -> vmcnt(0) drain -> lane0 2-B flag store (data visible first).
//  - consumer: poll line, then issue 32 h loads staged vmcnt(24/16/8/0).
//  - 2 syncthreads/step (around LDS K-reduction; 2nd is buf WAR).
__global__ __launch_bounds__(256, 1) void predictor_rnn(
    const unsigned short* __restrict__ wh_sw, const float* __restrict__ gtab,
    const int* __restrict__ y, const float* __restrict__ init,
    unsigned short* __restrict__ hs, unsigned short* __restrict__ flags) {
  __shared__ float buf[4][3][4][64][4];   // K-reduction exchange, 48 KB
  __shared__ unsigned short tbuf[1024];   // h store transpose, 2 KB (wave-private quarters)
  const int wg = blockIdx.x, tid = threadIdx.x, lane = tid & 63, w = tid >> 6;
  const int q = lane >> 4, dloc = lane & 15, dg = (wg << 4) + dloc;

  // Weight fragments -> registers (loop-invariant cached reads).
  h16x8 wrf[8], wzf[8], wnf[8];
#pragma unroll
  for (int i = 0; i < 8; ++i) {
    int kc = (w << 3) + i;
    wrf[i] = __builtin_bit_cast(h16x8, *(const s16x8*)(wh_sw + ((long)(      wg) << 14) + kc * 512 + lane * 8));
    wzf[i] = __builtin_bit_cast(h16x8, *(const s16x8*)(wh_sw + ((long)( 64 + wg) << 14) + kc * 512 + lane * 8));
    wnf[i] = __builtin_bit_cast(h16x8, *(const s16x8*)(wh_sw + ((long)(128 + wg) << 14) + kc * 512 + lane * 8));
  }
  float hreg[4];
#pragma unroll
  for (int j = 0; j < 4; ++j) hreg[j] = init[dg];

  // This wave's poll address (one ushort within its group's 128-B line) and
  // this wave's publish flag address.
  const unsigned short* fpoll = flags + (w << 6) + lane;
  unsigned short* fpub = flags + ((wg >> 4) << 6) + ((wg & 15) << 2) + w;

  for (int t = 1; t <= NT; ++t) {
    // ---- issue gate-table prefetch (drained for free by the poll) ----
    float gr[4], gz[4], gn[4];
#pragma unroll
    for (int j = 0; j < 4; ++j) {
      int b = (w << 4) + (q << 2) + j;
      int tok = (t == 1) ? 0 : y[b * NU + (t - 2)];
      const float* g = gtab + (long)tok * G3 + dg;
      asm volatile("global_load_dword %0, %1, off" : "=v"(gr[j]) : "v"(g) : "memory");
      asm volatile("global_load_dword %0, %1, off" : "=v"(gz[j]) : "v"(g + 1024) : "memory");
      asm volatile("global_load_dword %0, %1, off" : "=v"(gn[j]) : "v"(g + 2048) : "memory");
    }

    // ---- per-wave poll: ONE coalesced ushort load (single 128-B line) ----
    if (t > 1) {
      const unsigned int tm1 = (unsigned)(t - 1);
      for (;;) {
        unsigned int v;
        asm volatile("global_load_ushort %0, %1, off sc1" : "=v"(v) : "v"(fpoll) : "memory");
        asm volatile("s_waitcnt vmcnt(0)" : "+v"(v) :: "memory");
        if (__all((int)(v >= tm1))) break;
        __builtin_amdgcn_s_sleep(1);
      }
    }
    // tie gtab registers (vmcnt already 0 after the poll)
    asm volatile("s_waitcnt vmcnt(0)"
      : "+v"(gr[0]), "+v"(gr[1]), "+v"(gr[2]), "+v"(gr[3]),
        "+v"(gz[0]), "+v"(gz[1]), "+v"(gz[2]), "+v"(gz[3]),
        "+v"(gn[0]), "+v"(gn[1]), "+v"(gn[2]), "+v"(gn[3]) :: "memory");

    const unsigned short* hprev = hs + (long)(t - 1) * SLOT;
    unsigned short* hcur = hs + (long)t * SLOT;

    // ---- issue all 32 coherent h-fragment loads, consume in 4 staged groups ----
    i32x4 hf[32];
#pragma unroll
    for (int bg = 0; bg < 4; ++bg)
#pragma unroll
      for (int i = 0; i < 8; ++i) {
        const unsigned short* a = hprev + bg * 16384 + ((w << 3) + i) * 512 + lane * 8;
        asm volatile("global_load_dwordx4 %0, %1, off sc1" : "=v"(hf[bg * 8 + i]) : "v"(a) : "memory");
      }
    f32x4 aR[4], aZ[4], aN[4];
#pragma unroll
    for (int bg = 0; bg < 4; ++bg) { aR[bg] = (f32x4){0,0,0,0}; aZ[bg] = (f32x4){0,0,0,0}; aN[bg] = (f32x4){0,0,0,0}; }
    {
      PINSTAGE(24, 0);
#pragma unroll
      for (int i = 0; i < 8; ++i) { h16x8 a = __builtin_bit_cast(h16x8, hf[0 * 8 + i]);
        aR[0] = __builtin_amdgcn_mfma_f32_16x16x32_f16(a, wrf[i], aR[0], 0, 0, 0);
        aZ[0] = __builtin_amdgcn_mfma_f32_16x16x32_f16(a, wzf[i], aZ[0], 0, 0, 0);
        aN[0] = __builtin_amdgcn_mfma_f32_16x16x32_f16(a, wnf[i], aN[0], 0, 0, 0); }
      PINSTAGE(16, 1);
#pragma unroll
      for (int i = 0; i < 8; ++i) { h16x8 a = __builtin_bit_cast(h16x8, hf[1 * 8 + i]);
        aR[1] = __builtin_amdgcn_mfma_f32_16x16x32_f16(a, wrf[i], aR[1], 0, 0, 0);
        aZ[1] = __builtin_amdgcn_mfma_f32_16x16x32_f16(a, wzf[i], aZ[1], 0, 0, 0);
        aN[1] = __builtin_amdgcn_mfma_f32_16x16x32_f16(a, wnf[i], aN[1], 0, 0, 0); }
      PINSTAGE(8, 2);
#pragma unroll
      for (int i = 0; i < 8; ++i) { h16x8 a = __builtin_bit_cast(h16x8, hf[2 * 8 + i]);
        aR[2] = __builtin_amdgcn_mfma_f32_16x16x32_f16(a, wrf[i], aR[2], 0, 0, 0);
        aZ[2] = __builtin_amdgcn_mfma_f32_16x16x32_f16(a, wzf[i], aZ[2], 0, 0, 0);
        aN[2] = __builtin_amdgcn_mfma_f32_16x16x32_f16(a, wnf[i], aN[2], 0, 0, 0); }
      PINSTAGE(0, 3);
#pragma unroll
      for (int i = 0; i < 8; ++i) { h16x8 a = __builtin_bit_cast(h16x8, hf[3 * 8 + i]);
        aR[3] = __builtin_amdgcn_mfma_f32_16x16x32_f16(a, wrf[i], aR[3], 0, 0, 0);
        aZ[3] = __builtin_amdgcn_mfma_f32_16x16x32_f16(a, wzf[i], aZ[3], 0, 0, 0);
        aN[3] = __builtin_amdgcn_mfma_f32_16x16x32_f16(a, wnf[i], aN[3], 0, 0, 0); }
    }

    // ---- cross-wave K-reduction via LDS ----
#pragma unroll
    for (int b2 = 0; b2 < 4; ++b2)
      if (b2 != w) {
        *(f32x4*)&buf[w][0][b2][lane][0] = aR[b2];
        *(f32x4*)&buf[w][1][b2][lane][0] = aZ[b2];
        *(f32x4*)&buf[w][2][b2][lane][0] = aN[b2];
      }
    __syncthreads();
    f32x4 sR = aR[w], sZ = aZ[w], sN = aN[w];
#pragma unroll
    for (int v = 0; v < 4; ++v)
      if (v != w) {
        sR += *(const f32x4*)&buf[v][0][w][lane][0];
        sZ += *(const f32x4*)&buf[v][1][w][lane][0];
        sN += *(const f32x4*)&buf[v][2][w][lane][0];
      }
    __syncthreads();   // buf WAR protection vs next iteration's writes

    // ---- gate epilogue; fp32 h chain in registers; fp16 h to wave-private tbuf ----
#pragma unroll
    for (int j = 0; j < 4; ++j) {
      float r = 1.f / (1.f + __expf(-(gr[j] + sR[j])));
      float z = 1.f / (1.f + __expf(-(gz[j] + sZ[j])));
      float np = gn[j] + r * sN[j];
      float e2 = __expf(-2.f * fabsf(np));              // overflow-safe tanh
      float tn = (1.f - e2) / (1.f + e2);
      tn = np < 0.f ? -tn : tn;
      float hnew = (1.f - z) * tn + z * hreg[j];
      hreg[j] = hnew;
      tbuf[(w << 8) + ((((q << 2) + j) | ((dloc >> 3) << 4)) << 3) + (dloc & 7)] = f2h(hnew);
    }
    // wave-private transpose: wave-local LDS ordering is enough (no barrier)
    asm volatile("s_waitcnt lgkmcnt(0)" ::: "memory");

    // ---- per-wave publish: 512-B coalesced store -> drain -> 2-B flag ----
    {
      unsigned long long pv = *(const unsigned long long*)(tbuf + (w << 8) + lane * 4);
      unsigned short* gp = hcur + ((long)(w * 32 + (wg >> 1)) << 9) + ((wg & 1) << 8) + lane * 4;
      asm volatile("global_store_dwordx2 %0, %1, off sc1" :: "v"(gp), "v"(pv) : "memory");
      asm volatile("s_waitcnt vmcnt(0)" ::: "memory");
      if (lane == 0)
        asm volatile("global_store_short %0, %1, off sc1" :: "v"(fpub), "v"((unsigned)t) : "memory");
    }
  }
}

extern "C" void kernel_launch(void* const* d_in, const int* in_sizes, int n_in,
                              void* d_out, int out_size, void* d_ws, size_t ws_size,
                              hipStream_t stream) {
  const int*   y    = (const int*)d_in[0];
  const float* em   = (const float*)d_in[1];
  const float* wih  = (const float*)d_in[2];
  const float* bih  = (const float*)d_in[3];
  const float* whh  = (const float*)d_in[4];
  const float* bhh  = (const float*)d_in[5];
  const float* lw   = (const float*)d_in[6];
  const float* lb   = (const float*)d_in[7];
  const float* init = (const float*)d_in[8];
  float* out = (float*)d_out;

  char* ws = (char*)d_ws;
  size_t off = 0;
  auto alloc = [&](size_t n) { void* p = ws + off; off += (n + 255) & ~(size_t)255; return p; };
  unsigned short* wh_sw   = (unsigned short*)alloc(6291456);    // W_hh fp16 swizzled
  unsigned short* wi_sw   = (unsigned short*)alloc(6291456);    // W_ih fp16 swizzled
  unsigned short* em_sw   = (unsigned short*)alloc(2097152);    // embed fp16 swizzled
  unsigned short* lw_sw   = (unsigned short*)alloc(2097152);    // linear_w fp16 swizzled
  float*          gtab    = (float*)alloc(12582912);            // [V,3072] token gate table
  float*          bias_sum= (float*)alloc(12288);               // bias_ih + bias_hh
  unsigned int*   flags   = (unsigned int*)alloc(512);          // 4 packed ushort flag lines
  unsigned short* hs      = (unsigned short*)alloc(67371008UL); // 514 h slots, fp16 swizzled
  (void)ws_size; (void)in_sizes; (void)n_in; (void)out_size;

  predictor_prep<<<dim3(33037), dim3(256), 0, stream>>>(
      whh, wih, em, lw, bih, bhh, init, wh_sw, wi_sw, em_sw, lw_sw, bias_sum, hs, flags);
  predictor_gemm<<<dim3(48, 16), dim3(256), 0, stream>>>(
      em_sw, 65536L, wi_sw, bias_sum, gtab, /*rowmul_i=*/1, /*rowmul_c=*/64, /*stride=*/3072);
  predictor_rnn<<<dim3(NWG), dim3(256), 0, stream>>>(
      wh_sw, gtab, y, init, hs, (unsigned short*)flags);
  predictor_gemm<<<dim3(16, 513), dim3(256), 0, stream>>>(
      hs + 65536, 65536L, lw_sw, lb, out, /*rowmul_i=*/513, /*rowmul_c=*/1, /*stride=*/1024);
}